// Round 1
// baseline (1272.918 us; speedup 1.0000x reference)
//
#include <hip/hip_runtime.h>
#include <hip/hip_bf16.h>

namespace {

constexpr int kT = 51;      // input timesteps
constexpr int kOut = 20;    // decoder steps

typedef __attribute__((ext_vector_type(8))) short bf16x8;
typedef __attribute__((ext_vector_type(4))) float f32x4;

union FragU {
    bf16x8 v;
    unsigned long long u64[2];
    unsigned short s[8];
};

__device__ __forceinline__ unsigned short f2bf(float x) {
    union { float f; unsigned int u; } v;
    v.f = x;
    unsigned int r = (v.u + 0x7fffu + ((v.u >> 16) & 1u)) >> 16;
    return (unsigned short)r;
}

// Wave-level GRU enc-dec. 1 wave/block, 16 batch rows per wave.
// MFMA orientation: C[j][b] = sum_k A[j][k] * B[k][b]
//   A = weights (rows j = gate outputs), B = h^T (cols = batch).
// 16x16x32 bf16 MFMA layouts (HW-verified per guide):
//   A: lane(q,i) holds A[m=i][k=8q+jj]
//   B: lane(q,i) holds B[k=8q+jj][n=i]
//   C: lane(q,i) holds C[row=4q+r][col=i], r=0..3
__global__ __launch_bounds__(64, 2) void gru_encdec(
    const float* __restrict__ input,
    const float* __restrict__ eWih, const float* __restrict__ eWhh,
    const float* __restrict__ ebih, const float* __restrict__ ebhh,
    const float* __restrict__ dWih, const float* __restrict__ dWhh,
    const float* __restrict__ dbih, const float* __restrict__ dbhh,
    const float* __restrict__ linW, const float* __restrict__ linb,
    float* __restrict__ out)
{
    // per-wave h transpose buffer: 16 rows(batch) x 64 u, stride 68 bf16 (pad)
    __shared__ __align__(16) unsigned short hlds[16 * 68];

    const int lane = (int)(threadIdx.x & 63u);
    const int q = lane >> 4;
    const int i = lane & 15;
    const long b = (long)blockIdx.x * 16 + i;
    const float* __restrict__ xrow = input + b * (kT * 4);

    // Weight fragments (registers, reloaded per phase):
    // WA[tau][f]: Whh A-frag, tile tau (j rows 16*tau..+15), f = K-half (k 32f..32f+31)
    // WAUG[tau]:  augmented gi frag: cols [Wih(4), bias(1), 0...]; tau 0..7 -> r,z
    //             (bias = bih+bhh), tau 8..11 -> n (bias = bih only)
    bf16x8 WA[12][2];
    bf16x8 WAUG[12];
    float bhhn[16];   // bhh_n[128 + 16t + 4q + r] per lane
    float hprev[16];  // h fp32, C-layout: [t*4+r] = h[b=i][u=16t+4q+r]
    bf16x8 bh0 = {0, 0, 0, 0, 0, 0, 0, 0};  // B-frag: h[b=i][k=8q+jj]
    bf16x8 bh1 = {0, 0, 0, 0, 0, 0, 0, 0};  // B-frag: h[b=i][k=32+8q+jj]
    float px[4];
    const f32x4 z4 = {0.f, 0.f, 0.f, 0.f};

    auto load_whh = [&](const float* __restrict__ Whh) {
#pragma unroll
        for (int tau = 0; tau < 12; ++tau) {
#pragma unroll
            for (int f = 0; f < 2; ++f) {
                const float* p = Whh + (tau * 16 + i) * 64 + f * 32 + q * 8;
                FragU fu;
#pragma unroll
                for (int j = 0; j < 8; ++j) fu.s[j] = f2bf(p[j]);
                WA[tau][f] = fu.v;
            }
        }
    };

    auto load_aug = [&](const float* __restrict__ Wih,
                        const float* __restrict__ bih,
                        const float* __restrict__ bhh) {
#pragma unroll
        for (int tau = 0; tau < 12; ++tau) {
            FragU fu;
            fu.u64[0] = 0; fu.u64[1] = 0;
            if (q == 0) {
                int j = tau * 16 + i;
#pragma unroll
                for (int d = 0; d < 4; ++d) fu.s[d] = f2bf(Wih[j * 4 + d]);
                float bias = (tau < 8) ? (bih[j] + bhh[j]) : bih[j];
                fu.s[4] = f2bf(bias);
            }
            WAUG[tau] = fu.v;
        }
#pragma unroll
        for (int t = 0; t < 4; ++t)
#pragma unroll
            for (int r = 0; r < 4; ++r)
                bhhn[t * 4 + r] = bhh[128 + 16 * t + 4 * q + r];
    };

    auto make_baug = [&]() -> bf16x8 {
        FragU fu;
        fu.u64[0] = 0; fu.u64[1] = 0;
        if (q == 0) {
            fu.s[0] = f2bf(px[0]);
            fu.s[1] = f2bf(px[1]);
            fu.s[2] = f2bf(px[2]);
            fu.s[3] = f2bf(px[3]);
            fu.s[4] = 0x3f80;  // bf16(1.0) -> picks up the bias column
        }
        return fu.v;
    };

    // One GRU step: consumes bh0/bh1 (h state) + baug (px,1), updates hprev,
    // round-trips h' through per-wave LDS, reloads bh0/bh1 with h'.
    auto gru_step = [&](bf16x8 baug) {
#pragma unroll
        for (int t = 0; t < 4; ++t) {  // u-quarter: u = 16t + 4q + r
            f32x4 accR = __builtin_amdgcn_mfma_f32_16x16x32_bf16(WAUG[t], baug, z4, 0, 0, 0);
            accR = __builtin_amdgcn_mfma_f32_16x16x32_bf16(WA[t][0], bh0, accR, 0, 0, 0);
            accR = __builtin_amdgcn_mfma_f32_16x16x32_bf16(WA[t][1], bh1, accR, 0, 0, 0);
            f32x4 accZ = __builtin_amdgcn_mfma_f32_16x16x32_bf16(WAUG[4 + t], baug, z4, 0, 0, 0);
            accZ = __builtin_amdgcn_mfma_f32_16x16x32_bf16(WA[4 + t][0], bh0, accZ, 0, 0, 0);
            accZ = __builtin_amdgcn_mfma_f32_16x16x32_bf16(WA[4 + t][1], bh1, accZ, 0, 0, 0);
            f32x4 accNi = __builtin_amdgcn_mfma_f32_16x16x32_bf16(WAUG[8 + t], baug, z4, 0, 0, 0);
            f32x4 accNh = __builtin_amdgcn_mfma_f32_16x16x32_bf16(WA[8 + t][0], bh0, z4, 0, 0, 0);
            accNh = __builtin_amdgcn_mfma_f32_16x16x32_bf16(WA[8 + t][1], bh1, accNh, 0, 0, 0);

            unsigned short hb[4];
#pragma unroll
            for (int r = 0; r < 4; ++r) {
                float rr = 1.f / (1.f + __expf(-accR[r]));
                float zz = 1.f / (1.f + __expf(-accZ[r]));
                float hn = accNh[r] + bhhn[t * 4 + r];
                float pre = accNi[r] + rr * hn;          // accNi includes bih_n
                float e = __expf(2.f * pre);
                float nn = 1.f - 2.f / (e + 1.f);        // tanh(pre)
                float hp = hprev[t * 4 + r];
                float hv = nn + zz * (hp - nn);          // (1-z)n + z h
                hprev[t * 4 + r] = hv;
                hb[r] = f2bf(hv);
            }
            unsigned int w0 = (unsigned int)hb[0] | ((unsigned int)hb[1] << 16);
            unsigned int w1 = (unsigned int)hb[2] | ((unsigned int)hb[3] << 16);
            uint2 wv; wv.x = w0; wv.y = w1;
            *(uint2*)&hlds[i * 68 + 16 * t + 4 * q] = wv;  // h'[b=i][u=16t+4q ..+3]
        }
        // reload B-frags with new h (same-wave LDS, in-order, no barrier)
        FragU f0, f1;
        f0.u64[0] = *(const unsigned long long*)&hlds[i * 68 + 8 * q];
        f0.u64[1] = *(const unsigned long long*)&hlds[i * 68 + 8 * q + 4];
        f1.u64[0] = *(const unsigned long long*)&hlds[i * 68 + 32 + 8 * q];
        f1.u64[1] = *(const unsigned long long*)&hlds[i * 68 + 32 + 8 * q + 4];
        bh0 = f0.v;
        bh1 = f1.v;
    };

    // ---------------- encoder ----------------
#pragma unroll
    for (int t = 0; t < 16; ++t) hprev[t] = 0.f;
    load_whh(eWhh);
    load_aug(eWih, ebih, ebhh);

    float4 xp = *(const float4*)(xrow);  // input[b][0][:]
#pragma unroll 1
    for (int s = 0; s < kT - 1; ++s) {
        float4 xc = *(const float4*)(xrow + (s + 1) * 4);
        px[0] = xc.x - xp.x;
        px[1] = xc.y - xp.y;
        px[2] = xc.z - xp.z;
        px[3] = xc.w - xp.w;
        xp = xc;
        gru_step(make_baug());
    }
    // px now holds diffs[b][T-2] = decoder's initial px

    // ---------------- decoder ----------------
    load_whh(dWhh);
    load_aug(dWih, dbih, dbhh);

    // linear head frags: A rows m=i (rows >=4 zero), cols = [linW(64) | -, linb]
    bf16x8 AL0, AL1, AL2;
    {
        FragU a0, a1, a2;
        a0.u64[0] = a0.u64[1] = 0;
        a1.u64[0] = a1.u64[1] = 0;
        a2.u64[0] = a2.u64[1] = 0;
        if (i < 4) {
            const float* p0 = linW + i * 64 + q * 8;
            const float* p1 = linW + i * 64 + 32 + q * 8;
#pragma unroll
            for (int j = 0; j < 8; ++j) {
                a0.s[j] = f2bf(p0[j]);
                a1.s[j] = f2bf(p1[j]);
            }
            if (q == 0) a2.s[4] = f2bf(linb[i]);  // bias column only (px added in fp32)
        }
        AL0 = a0.v; AL1 = a1.v; AL2 = a2.v;
    }
    float4 offv = *(const float4*)(xrow + 50 * 4);  // input[b][T-1][:]

#pragma unroll 1
    for (int s = 0; s < kOut; ++s) {
        bf16x8 baug = make_baug();
        gru_step(baug);  // bh0/bh1 now hold the NEW h
        f32x4 accX = __builtin_amdgcn_mfma_f32_16x16x32_bf16(AL2, baug, z4, 0, 0, 0);
        accX = __builtin_amdgcn_mfma_f32_16x16x32_bf16(AL0, bh0, accX, 0, 0, 0);
        accX = __builtin_amdgcn_mfma_f32_16x16x32_bf16(AL1, bh1, accX, 0, 0, 0);
        if (q == 0) {
            // C rows 0..3 = output dims d; col = b = i
            float x0 = accX[0] + px[0];
            float x1 = accX[1] + px[1];
            float x2 = accX[2] + px[2];
            float x3 = accX[3] + px[3];
            float4 o;
            o.x = x0 + offv.x;
            o.y = x1 + offv.y;
            o.z = x2 + offv.z;
            o.w = x3 + offv.w;
            *(float4*)(out + b * (kOut * 4) + s * 4) = o;
            px[0] = x0; px[1] = x1; px[2] = x2; px[3] = x3;  // fp32 px chain
        }
    }
}

}  // namespace

extern "C" void kernel_launch(void* const* d_in, const int* in_sizes, int n_in,
                              void* d_out, int out_size, void* d_ws, size_t ws_size,
                              hipStream_t stream) {
    const float* input = (const float*)d_in[0];
    const float* eWih = (const float*)d_in[1];
    const float* eWhh = (const float*)d_in[2];
    const float* ebih = (const float*)d_in[3];
    const float* ebhh = (const float*)d_in[4];
    const float* dWih = (const float*)d_in[5];
    const float* dWhh = (const float*)d_in[6];
    const float* dbih = (const float*)d_in[7];
    const float* dbhh = (const float*)d_in[8];
    const float* linW = (const float*)d_in[9];
    const float* linb = (const float*)d_in[10];
    float* out = (float*)d_out;

    const int B = in_sizes[0] / (kT * 4);
    const int nblocks = B / 16;
    gru_encdec<<<nblocks, 64, 0, stream>>>(input, eWih, eWhh, ebih, ebhh,
                                           dWih, dWhh, dbih, dbhh,
                                           linW, linb, out);
}

// Round 3
// 753.325 us; speedup vs baseline: 1.6897x; 1.6897x over previous
//
#include <hip/hip_runtime.h>
#include <hip/hip_bf16.h>

namespace {

constexpr int kT = 51;      // input timesteps
constexpr int kOut = 20;    // decoder steps
constexpr float kL2E  = 1.4426950408889634f;   // log2(e)
constexpr float kL2E2 = 2.8853900817779268f;   // 2*log2(e)

typedef __attribute__((ext_vector_type(8))) short bf16x8;
typedef __attribute__((ext_vector_type(4))) float f32x4;

union FragU {
    bf16x8 v;
    unsigned long long u64[2];
    unsigned int u32[4];
    unsigned short s[8];
};

__device__ __forceinline__ unsigned short f2bf(float x) {
    union { float f; unsigned int u; } v;
    v.f = x;
    unsigned int r = (v.u + 0x7fffu + ((v.u >> 16) & 1u)) >> 16;
    return (unsigned short)r;
}

// pack two floats to bf16x2 (low = bf(a), high = bf(b)), round-half-up:
// 2x v_add_u32 + 1x v_perm_b32
__device__ __forceinline__ unsigned int packbf(float a, float b) {
    union { float f; unsigned int u; } ua, ub;
    ua.f = a; ub.f = b;
    return __builtin_amdgcn_perm(ub.u + 0x8000u, ua.u + 0x8000u, 0x07060302u);
}

// Wave-level GRU enc-dec. 4 independent waves/block, 16 batch rows per wave.
// MFMA orientation: C[j][b] = sum_k A[j][k] * B[k][b]
//   A = weights (rows j = gate outputs), B = h^T (cols = batch).
// 16x16x32 bf16 MFMA layouts (HW-verified per guide):
//   A: lane(q,i) holds A[m=i][k=8q+jj]
//   B: lane(q,i) holds B[k=8q+jj][n=i]
//   C: lane(q,i) holds C[row=4q+r][col=i], r=0..3
// Weights are pre-scaled by log2(e) (r,z rows) / 2*log2(e) (n rows) so the
// activations use raw v_exp_f32 (2^x) with free neg modifiers.
__global__ __launch_bounds__(256, 2) void gru_encdec(
    const float* __restrict__ input,
    const float* __restrict__ eWih, const float* __restrict__ eWhh,
    const float* __restrict__ ebih, const float* __restrict__ ebhh,
    const float* __restrict__ dWih, const float* __restrict__ dWhh,
    const float* __restrict__ dbih, const float* __restrict__ dbhh,
    const float* __restrict__ linW, const float* __restrict__ linb,
    float* __restrict__ out)
{
    // per-wave h transpose buffer: 16 rows(batch) x 64 u, stride 68 bf16 (pad)
    __shared__ __align__(16) unsigned short hlds[4][16 * 68];
    // per-wave decoder output staging: 16 rows x 80 floats, stride 84 (pad)
    __shared__ __align__(16) float sout[4][16 * 84];

    const int lane = (int)(threadIdx.x & 63u);
    const int wid = (int)(threadIdx.x >> 6u);
    const int q = lane >> 4;
    const int i = lane & 15;
    const long b = (long)blockIdx.x * 64 + wid * 16 + i;
    const float* __restrict__ xrow = input + b * (kT * 4);
    unsigned short* __restrict__ hl = hlds[wid];
    float* __restrict__ so = sout[wid];

    // Weight fragments (registers, reloaded per phase):
    // WA[tau][f]: Whh A-frag, tile tau (j rows 16*tau..+15), f = K-half
    // WAUG[tau]:  augmented gi frag: cols [Wih(4), bias(1), 0...]; tau 0..7 ->
    //             r,z (bias = (bih+bhh)*l2e), tau 8..11 -> n (bias = bih*2l2e)
    bf16x8 WA[12][2];
    bf16x8 WAUG[12];
    f32x4 bhhn4[4];   // bhh_n[128 + 16t + 4q + r] * 2l2e, MFMA C-init layout
    float hprev[16];  // h fp32, C-layout: [t*4+r] = h[b=i][u=16t+4q+r]
    bf16x8 bh0 = {0, 0, 0, 0, 0, 0, 0, 0};  // B-frag: h[b=i][k=8q+jj]
    bf16x8 bh1 = {0, 0, 0, 0, 0, 0, 0, 0};  // B-frag: h[b=i][k=32+8q+jj]
    float px[4];
    const f32x4 z4 = {0.f, 0.f, 0.f, 0.f};
    const bool q0 = (q == 0);

    auto load_whh = [&](const float* __restrict__ Whh) {
#pragma unroll
        for (int tau = 0; tau < 12; ++tau) {
            const float sc = (tau < 8) ? kL2E : kL2E2;
#pragma unroll
            for (int f = 0; f < 2; ++f) {
                const float* p = Whh + (tau * 16 + i) * 64 + f * 32 + q * 8;
                FragU fu;
#pragma unroll
                for (int j = 0; j < 8; ++j) fu.s[j] = f2bf(p[j] * sc);
                WA[tau][f] = fu.v;
            }
        }
    };

    auto load_aug = [&](const float* __restrict__ Wih,
                        const float* __restrict__ bih,
                        const float* __restrict__ bhh) {
#pragma unroll
        for (int tau = 0; tau < 12; ++tau) {
            const float sc = (tau < 8) ? kL2E : kL2E2;
            FragU fu;
            fu.u64[0] = 0; fu.u64[1] = 0;
            if (q0) {
                int j = tau * 16 + i;
#pragma unroll
                for (int d = 0; d < 4; ++d) fu.s[d] = f2bf(Wih[j * 4 + d] * sc);
                float bias = (tau < 8) ? (bih[j] + bhh[j]) : bih[j];
                fu.s[4] = f2bf(bias * sc);
            }
            WAUG[tau] = fu.v;
        }
#pragma unroll
        for (int t = 0; t < 4; ++t)
#pragma unroll
            for (int r = 0; r < 4; ++r)
                bhhn4[t][r] = bhh[128 + 16 * t + 4 * q + r] * kL2E2;
    };

    auto make_baug = [&]() -> bf16x8 {
        FragU fu;
        unsigned int p01 = packbf(px[0], px[1]);
        unsigned int p23 = packbf(px[2], px[3]);
        fu.u32[0] = q0 ? p01 : 0u;
        fu.u32[1] = q0 ? p23 : 0u;
        fu.u32[2] = q0 ? 0x3f80u : 0u;  // bf16(1.0) in s[4] -> bias column
        fu.u32[3] = 0u;
        return fu.v;
    };

    // One GRU step: consumes bh0/bh1 (h state) + baug (px,1), updates hprev,
    // round-trips h' through per-wave LDS, reloads bh0/bh1 with h'.
    auto gru_step = [&](bf16x8 baug) {
#pragma unroll
        for (int t = 0; t < 4; ++t) {  // u-quarter: u = 16t + 4q + r
            f32x4 accR = __builtin_amdgcn_mfma_f32_16x16x32_bf16(WAUG[t], baug, z4, 0, 0, 0);
            accR = __builtin_amdgcn_mfma_f32_16x16x32_bf16(WA[t][0], bh0, accR, 0, 0, 0);
            accR = __builtin_amdgcn_mfma_f32_16x16x32_bf16(WA[t][1], bh1, accR, 0, 0, 0);
            f32x4 accZ = __builtin_amdgcn_mfma_f32_16x16x32_bf16(WAUG[4 + t], baug, z4, 0, 0, 0);
            accZ = __builtin_amdgcn_mfma_f32_16x16x32_bf16(WA[4 + t][0], bh0, accZ, 0, 0, 0);
            accZ = __builtin_amdgcn_mfma_f32_16x16x32_bf16(WA[4 + t][1], bh1, accZ, 0, 0, 0);
            f32x4 accNi = __builtin_amdgcn_mfma_f32_16x16x32_bf16(WAUG[8 + t], baug, z4, 0, 0, 0);
            // C-init = bhh_n (pre-scaled): folds the bias add into the MFMA
            f32x4 accNh = __builtin_amdgcn_mfma_f32_16x16x32_bf16(WA[8 + t][0], bh0, bhhn4[t], 0, 0, 0);
            accNh = __builtin_amdgcn_mfma_f32_16x16x32_bf16(WA[8 + t][1], bh1, accNh, 0, 0, 0);

            float hv[4];
#pragma unroll
            for (int r = 0; r < 4; ++r) {
                // sigmoid(x) with acc = x*log2e: 1/(1 + 2^-acc)
                float rr = __builtin_amdgcn_rcpf(1.f + __builtin_amdgcn_exp2f(-accR[r]));
                float zz = __builtin_amdgcn_rcpf(1.f + __builtin_amdgcn_exp2f(-accZ[r]));
                // tanh(pre) with pre2 = 2*log2e*pre: 1 - 2/(2^pre2 + 1)
                float pre2 = __builtin_fmaf(rr, accNh[r], accNi[r]);
                float tt = __builtin_amdgcn_rcpf(__builtin_amdgcn_exp2f(pre2) + 1.f);
                float nn = __builtin_fmaf(-2.f, tt, 1.f);
                float hp = hprev[t * 4 + r];
                hv[r] = __builtin_fmaf(zz, hp - nn, nn);  // (1-z)n + z h
                hprev[t * 4 + r] = hv[r];
            }
            uint2 wv;
            wv.x = packbf(hv[0], hv[1]);
            wv.y = packbf(hv[2], hv[3]);
            *(uint2*)&hl[i * 68 + 16 * t + 4 * q] = wv;  // h'[b=i][u=16t+4q..+3]
        }
        // reload B-frags with new h (same-wave LDS, in-order, no barrier)
        FragU f0, f1;
        f0.u64[0] = *(const unsigned long long*)&hl[i * 68 + 8 * q];
        f0.u64[1] = *(const unsigned long long*)&hl[i * 68 + 8 * q + 4];
        f1.u64[0] = *(const unsigned long long*)&hl[i * 68 + 32 + 8 * q];
        f1.u64[1] = *(const unsigned long long*)&hl[i * 68 + 32 + 8 * q + 4];
        bh0 = f0.v;
        bh1 = f1.v;
    };

    // ---------------- encoder ----------------
#pragma unroll
    for (int t = 0; t < 16; ++t) hprev[t] = 0.f;
    load_whh(eWhh);
    load_aug(eWih, ebih, ebhh);

    // depth-1 prefetch of the input row (x[s+2] in flight during step s)
    float4 xp = *(const float4*)(xrow);
    float4 xn = *(const float4*)(xrow + 4);
#pragma unroll 1
    for (int s = 0; s < kT - 1; ++s) {
        int idx = s + 2; if (idx > kT - 1) idx = kT - 1;
        float4 xf = *(const float4*)(xrow + idx * 4);
        px[0] = xn.x - xp.x;
        px[1] = xn.y - xp.y;
        px[2] = xn.z - xp.z;
        px[3] = xn.w - xp.w;
        gru_step(make_baug());
        xp = xn;
        xn = xf;
    }
    // px = diffs[b][T-2] (decoder's initial px); xp = input[b][T-1] (offset)
    float4 offv = xp;

    // ---------------- decoder ----------------
    load_whh(dWhh);
    load_aug(dWih, dbih, dbhh);

    // linear head frags: A rows m=i (rows >=4 zero), col 64.. : [ -, linb]
    bf16x8 AL0, AL1, AL2;
    {
        FragU a0, a1, a2;
        a0.u64[0] = a0.u64[1] = 0;
        a1.u64[0] = a1.u64[1] = 0;
        a2.u64[0] = a2.u64[1] = 0;
        if (i < 4) {
            const float* p0 = linW + i * 64 + q * 8;
            const float* p1 = linW + i * 64 + 32 + q * 8;
#pragma unroll
            for (int j = 0; j < 8; ++j) {
                a0.s[j] = f2bf(p0[j]);
                a1.s[j] = f2bf(p1[j]);
            }
            if (q0) a2.s[4] = f2bf(linb[i]);  // bias col (px added in fp32)
        }
        AL0 = a0.v; AL1 = a1.v; AL2 = a2.v;
    }

#pragma unroll 1
    for (int s = 0; s < kOut; ++s) {
        bf16x8 baug = make_baug();
        gru_step(baug);  // bh0/bh1 now hold the NEW h
        f32x4 accX = __builtin_amdgcn_mfma_f32_16x16x32_bf16(AL2, baug, z4, 0, 0, 0);
        accX = __builtin_amdgcn_mfma_f32_16x16x32_bf16(AL0, bh0, accX, 0, 0, 0);
        accX = __builtin_amdgcn_mfma_f32_16x16x32_bf16(AL1, bh1, accX, 0, 0, 0);
        if (q0) {
            // C rows 0..3 = output dims d; col = b = i. fp32 px chain.
            float x0 = accX[0] + px[0];
            float x1 = accX[1] + px[1];
            float x2 = accX[2] + px[2];
            float x3 = accX[3] + px[3];
            float* sr = so + i * 84 + s * 4;
            sr[0] = x0 + offv.x;
            sr[1] = x1 + offv.y;
            sr[2] = x2 + offv.z;
            sr[3] = x3 + offv.w;
            px[0] = x0; px[1] = x1; px[2] = x2; px[3] = x3;
        }
    }

    // coalesced per-wave output flush: 16 rows x 80 floats (stride-84 in LDS)
    {
        float* __restrict__ go = out + ((long)blockIdx.x * 64 + wid * 16) * (kOut * 4);
#pragma unroll
        for (int it = 0; it < 5; ++it) {
            int g = it * 256 + lane * 4;       // flat float index in wave slice
            int row = g / 80;
            int e = g - row * 80;
            float4 v = *(const float4*)&so[row * 84 + e];
            *(float4*)&go[g] = v;
        }
    }
}

}  // namespace

extern "C" void kernel_launch(void* const* d_in, const int* in_sizes, int n_in,
                              void* d_out, int out_size, void* d_ws, size_t ws_size,
                              hipStream_t stream) {
    const float* input = (const float*)d_in[0];
    const float* eWih = (const float*)d_in[1];
    const float* eWhh = (const float*)d_in[2];
    const float* ebih = (const float*)d_in[3];
    const float* ebhh = (const float*)d_in[4];
    const float* dWih = (const float*)d_in[5];
    const float* dWhh = (const float*)d_in[6];
    const float* dbih = (const float*)d_in[7];
    const float* dbhh = (const float*)d_in[8];
    const float* linW = (const float*)d_in[9];
    const float* linb = (const float*)d_in[10];
    float* out = (float*)d_out;

    const int B = in_sizes[0] / (kT * 4);
    const int nblocks = B / 64;
    gru_encdec<<<nblocks, 256, 0, stream>>>(input, eWih, eWhh, ebih, ebhh,
                                            dWih, dWhh, dbih, dbhh,
                                            linW, linb, out);
}

// Round 4
// 685.980 us; speedup vs baseline: 1.8556x; 1.0982x over previous
//
#include <hip/hip_runtime.h>
#include <hip/hip_bf16.h>

namespace {

constexpr int kT = 51;      // input timesteps
constexpr int kOut = 20;    // decoder steps
constexpr float kL2E  = 1.4426950408889634f;   // log2(e)
constexpr float kL2E2 = 2.8853900817779268f;   // 2*log2(e)

typedef __attribute__((ext_vector_type(8))) short bf16x8;
typedef __attribute__((ext_vector_type(4))) float f32x4;

union FragU {
    bf16x8 v;
    unsigned long long u64[2];
    unsigned int u32[4];
    unsigned short s[8];
};

__device__ __forceinline__ unsigned short f2bf(float x) {
    union { float f; unsigned int u; } v;
    v.f = x;
    unsigned int r = (v.u + 0x7fffu + ((v.u >> 16) & 1u)) >> 16;
    return (unsigned short)r;
}

// pack two floats to bf16x2 (low=bf(a), high=bf(b)): 2x v_add_u32 + v_perm_b32
__device__ __forceinline__ unsigned int packbf(float a, float b) {
    union { float f; unsigned int u; } ua, ub;
    ua.f = a; ub.f = b;
    return __builtin_amdgcn_perm(ub.u + 0x8000u, ua.u + 0x8000u, 0x07060302u);
}

// GRU enc-dec, wave-pair split. Block = 256 thr = 4 waves = 2 pairs.
// Pair p handles batch rows block*32 + p*16 + i (i = lane&15).
// Within a pair, wave half w owns hidden units [32w, 32w+32) -> its 6 W-row
// tiles (r: 2w,2w+1; z: 4+2w,..; n: 8+2w,..). Both waves need the FULL h as
// the MFMA B operand, so h' halves are exchanged through double-buffered LDS
// with one __syncthreads per step.
// MFMA 16x16x32 layouts: A lane(q,i)=A[m=i][k=8q+j]; B lane(q,i)=B[k=8q+j][n=i];
// C lane(q,i)=C[row=4q+r][col=i]. Weights pre-scaled by log2e (r,z) / 2log2e (n)
// so activations use raw v_exp_f32.
__global__ __launch_bounds__(256, 3) void gru_encdec(
    const float* __restrict__ input,
    const float* __restrict__ eWih, const float* __restrict__ eWhh,
    const float* __restrict__ ebih, const float* __restrict__ ebhh,
    const float* __restrict__ dWih, const float* __restrict__ dWhh,
    const float* __restrict__ dbih, const float* __restrict__ dbhh,
    const float* __restrict__ linW, const float* __restrict__ linb,
    float* __restrict__ out)
{
    // h exchange: [pair][dbuf][16 rows x 64 units, stride 68 bf16]
    __shared__ __align__(16) unsigned short hbuf[2][2][16 * 68];
    // decoder output staging: [pair][16 rows x 80 floats, stride 84]
    __shared__ __align__(16) float sout[2][16 * 84];

    const int lane = (int)(threadIdx.x & 63u);
    const int wid = (int)(threadIdx.x >> 6u);
    const int p = wid >> 1;      // pair id
    const int w = wid & 1;       // unit-half
    const int q = lane >> 4;
    const int i = lane & 15;
    const long b = (long)blockIdx.x * 32 + p * 16 + i;
    const float* __restrict__ xrow = input + b * (kT * 4);
    const bool q0 = (q == 0);

    // Per-wave weight fragments (6 tiles: local l=0,1 r; 2,3 z; 4,5 n)
    // global tile: gt(l) = (l<2 ? 2w+l : l<4 ? 4+2w+(l-2) : 8+2w+(l-4))
    bf16x8 WA[6][2];     // Whh frags, [l][K-half]
    bf16x8 WAUG[6];      // [Wih(4) | bias | 0...] frags (q0 lanes only)
    f32x4 bhhn4[2];      // bhh_n * 2l2e as C-init, per local n-tile t
    float hprev[8];      // fp32 h, [t*4+r] = h[b=i][u=32w+16t+4q+r]
    bf16x8 bh0 = {0, 0, 0, 0, 0, 0, 0, 0};  // B-frag h[b=i][k=8q+j]
    bf16x8 bh1 = {0, 0, 0, 0, 0, 0, 0, 0};  // B-frag h[b=i][k=32+8q+j]
    float px[4];
    const f32x4 z4 = {0.f, 0.f, 0.f, 0.f};
    int sel = 0;  // LDS h dbuf selector (uniform across block)

    auto gtile = [&](int l) -> int {
        return (l < 2) ? (2 * w + l) : (l < 4) ? (4 + 2 * w + l - 2)
                                               : (8 + 2 * w + l - 4);
    };

    auto load_whh = [&](const float* __restrict__ Whh) {
#pragma unroll
        for (int l = 0; l < 6; ++l) {
            const int tau = gtile(l);
            const float sc = (l < 4) ? kL2E : kL2E2;
#pragma unroll
            for (int f = 0; f < 2; ++f) {
                const float* ptr = Whh + (tau * 16 + i) * 64 + f * 32 + q * 8;
                FragU fu;
#pragma unroll
                for (int j = 0; j < 8; ++j) fu.s[j] = f2bf(ptr[j] * sc);
                WA[l][f] = fu.v;
            }
        }
    };

    auto load_aug = [&](const float* __restrict__ Wih,
                        const float* __restrict__ bih,
                        const float* __restrict__ bhh) {
#pragma unroll
        for (int l = 0; l < 6; ++l) {
            const int tau = gtile(l);
            const float sc = (l < 4) ? kL2E : kL2E2;
            FragU fu;
            fu.u64[0] = 0; fu.u64[1] = 0;
            if (q0) {
                int j = tau * 16 + i;
#pragma unroll
                for (int d = 0; d < 4; ++d) fu.s[d] = f2bf(Wih[j * 4 + d] * sc);
                float bias = (l < 4) ? (bih[j] + bhh[j]) : bih[j];
                fu.s[4] = f2bf(bias * sc);
            }
            WAUG[l] = fu.v;
        }
#pragma unroll
        for (int t = 0; t < 2; ++t)
#pragma unroll
            for (int r = 0; r < 4; ++r)
                bhhn4[t][r] = bhh[128 + 32 * w + 16 * t + 4 * q + r] * kL2E2;
    };

    auto make_baug = [&]() -> bf16x8 {
        FragU fu;
        unsigned int p01 = packbf(px[0], px[1]);
        unsigned int p23 = packbf(px[2], px[3]);
        fu.u32[0] = q0 ? p01 : 0u;
        fu.u32[1] = q0 ? p23 : 0u;
        fu.u32[2] = q0 ? 0x3f80u : 0u;  // bf16(1.0) -> bias column
        fu.u32[3] = 0u;
        return fu.v;
    };

    // One GRU step: this wave computes h' for its 32 units, exchanges halves
    // through LDS (1 barrier), reloads full-h B-frags.
    auto gru_step = [&](bf16x8 baug) {
        unsigned short* __restrict__ hw = hbuf[p][sel];
#pragma unroll
        for (int t = 0; t < 2; ++t) {  // local u-tile: u = 32w + 16t + 4q + r
            f32x4 accR = __builtin_amdgcn_mfma_f32_16x16x32_bf16(WAUG[t], baug, z4, 0, 0, 0);
            accR = __builtin_amdgcn_mfma_f32_16x16x32_bf16(WA[t][0], bh0, accR, 0, 0, 0);
            accR = __builtin_amdgcn_mfma_f32_16x16x32_bf16(WA[t][1], bh1, accR, 0, 0, 0);
            f32x4 accZ = __builtin_amdgcn_mfma_f32_16x16x32_bf16(WAUG[2 + t], baug, z4, 0, 0, 0);
            accZ = __builtin_amdgcn_mfma_f32_16x16x32_bf16(WA[2 + t][0], bh0, accZ, 0, 0, 0);
            accZ = __builtin_amdgcn_mfma_f32_16x16x32_bf16(WA[2 + t][1], bh1, accZ, 0, 0, 0);
            f32x4 accNi = __builtin_amdgcn_mfma_f32_16x16x32_bf16(WAUG[4 + t], baug, z4, 0, 0, 0);
            f32x4 accNh = __builtin_amdgcn_mfma_f32_16x16x32_bf16(WA[4 + t][0], bh0, bhhn4[t], 0, 0, 0);
            accNh = __builtin_amdgcn_mfma_f32_16x16x32_bf16(WA[4 + t][1], bh1, accNh, 0, 0, 0);

            float hv[4];
#pragma unroll
            for (int r = 0; r < 4; ++r) {
                float rr = __builtin_amdgcn_rcpf(1.f + __builtin_amdgcn_exp2f(-accR[r]));
                float zz = __builtin_amdgcn_rcpf(1.f + __builtin_amdgcn_exp2f(-accZ[r]));
                float pre2 = __builtin_fmaf(rr, accNh[r], accNi[r]);
                float tt = __builtin_amdgcn_rcpf(__builtin_amdgcn_exp2f(pre2) + 1.f);
                float nn = __builtin_fmaf(-2.f, tt, 1.f);
                float hp = hprev[t * 4 + r];
                hv[r] = __builtin_fmaf(zz, hp - nn, nn);
                hprev[t * 4 + r] = hv[r];
            }
            uint2 wv;
            wv.x = packbf(hv[0], hv[1]);
            wv.y = packbf(hv[2], hv[3]);
            *(uint2*)&hw[i * 68 + 32 * w + 16 * t + 4 * q] = wv;
        }
        __syncthreads();  // h' halves visible block-wide
        FragU f0, f1;
        f0.u64[0] = *(const unsigned long long*)&hw[i * 68 + 8 * q];
        f0.u64[1] = *(const unsigned long long*)&hw[i * 68 + 8 * q + 4];
        f1.u64[0] = *(const unsigned long long*)&hw[i * 68 + 32 + 8 * q];
        f1.u64[1] = *(const unsigned long long*)&hw[i * 68 + 32 + 8 * q + 4];
        bh0 = f0.v;
        bh1 = f1.v;
        sel ^= 1;
    };

    // ---------------- encoder ----------------
#pragma unroll
    for (int t = 0; t < 8; ++t) hprev[t] = 0.f;
    load_whh(eWhh);
    load_aug(eWih, ebih, ebhh);

    float4 xp = *(const float4*)(xrow);
    float4 xn = *(const float4*)(xrow + 4);
#pragma unroll 1
    for (int s = 0; s < kT - 1; ++s) {
        int idx = s + 2; if (idx > kT - 1) idx = kT - 1;
        float4 xf = *(const float4*)(xrow + idx * 4);
        px[0] = xn.x - xp.x;
        px[1] = xn.y - xp.y;
        px[2] = xn.z - xp.z;
        px[3] = xn.w - xp.w;
        gru_step(make_baug());
        xp = xn;
        xn = xf;
    }
    float4 offv = xp;  // input[b][T-1]; px = diffs[b][T-2]

    // ---------------- decoder ----------------
    load_whh(dWhh);
    load_aug(dWih, dbih, dbhh);

    // linear head frags (held by BOTH waves; head computed redundantly so the
    // fp32 px chain stays wave-local)
    bf16x8 AL0, AL1, AL2;
    {
        FragU a0, a1, a2;
        a0.u64[0] = a0.u64[1] = 0;
        a1.u64[0] = a1.u64[1] = 0;
        a2.u64[0] = a2.u64[1] = 0;
        if (i < 4) {
            const float* p0 = linW + i * 64 + q * 8;
            const float* p1 = linW + i * 64 + 32 + q * 8;
#pragma unroll
            for (int j = 0; j < 8; ++j) {
                a0.s[j] = f2bf(p0[j]);
                a1.s[j] = f2bf(p1[j]);
            }
            if (q0) a2.s[4] = f2bf(linb[i]);
        }
        AL0 = a0.v; AL1 = a1.v; AL2 = a2.v;
    }
    float* __restrict__ so = sout[p];

#pragma unroll 1
    for (int s = 0; s < kOut; ++s) {
        bf16x8 baug = make_baug();
        gru_step(baug);  // bh0/bh1 = NEW full h
        f32x4 accX = __builtin_amdgcn_mfma_f32_16x16x32_bf16(AL2, baug, z4, 0, 0, 0);
        accX = __builtin_amdgcn_mfma_f32_16x16x32_bf16(AL0, bh0, accX, 0, 0, 0);
        accX = __builtin_amdgcn_mfma_f32_16x16x32_bf16(AL1, bh1, accX, 0, 0, 0);
        float x0 = accX[0] + px[0];
        float x1 = accX[1] + px[1];
        float x2 = accX[2] + px[2];
        float x3 = accX[3] + px[3];
        if (w == 0 && q0) {
            float* sr = so + i * 84 + s * 4;
            sr[0] = x0 + offv.x;
            sr[1] = x1 + offv.y;
            sr[2] = x2 + offv.z;
            sr[3] = x3 + offv.w;
        }
        px[0] = x0; px[1] = x1; px[2] = x2; px[3] = x3;
    }

    // coalesced flush: w==0 wave writes its pair's 16 rows x 80 floats.
    // sout was written by this same wave -> no extra barrier needed.
    if (w == 0) {
        float* __restrict__ go = out + ((long)blockIdx.x * 32 + p * 16) * (kOut * 4);
#pragma unroll
        for (int it = 0; it < 5; ++it) {
            int g = it * 256 + lane * 4;
            int row = g / 80;
            int e = g - row * 80;
            float4 v = *(const float4*)&so[row * 84 + e];
            *(float4*)&go[g] = v;
        }
    }
}

}  // namespace

extern "C" void kernel_launch(void* const* d_in, const int* in_sizes, int n_in,
                              void* d_out, int out_size, void* d_ws, size_t ws_size,
                              hipStream_t stream) {
    const float* input = (const float*)d_in[0];
    const float* eWih = (const float*)d_in[1];
    const float* eWhh = (const float*)d_in[2];
    const float* ebih = (const float*)d_in[3];
    const float* ebhh = (const float*)d_in[4];
    const float* dWih = (const float*)d_in[5];
    const float* dWhh = (const float*)d_in[6];
    const float* dbih = (const float*)d_in[7];
    const float* dbhh = (const float*)d_in[8];
    const float* linW = (const float*)d_in[9];
    const float* linb = (const float*)d_in[10];
    float* out = (float*)d_out;

    const int B = in_sizes[0] / (kT * 4);
    const int nblocks = B / 32;
    gru_encdec<<<nblocks, 256, 0, stream>>>(input, eWih, eWhh, ebih, ebhh,
                                            dWih, dWhh, dbih, dbhh,
                                            linW, linb, out);
}